// Round 2
// baseline (144.936 us; speedup 1.0000x reference)
//
#include <hip/hip_runtime.h>
#include <hip/hip_cooperative_groups.h>
#include <math.h>

namespace cg = cooperative_groups;

#define NS 512
#define DE 512
#define NCL 5
#define NBLK 256

// ws layout: cosmat[512*512] | psum[256] | pnz[256]   (fully rewritten each launch)

// ---------------------------------------------------------------------------
// ONE cooperative kernel: gram (each element once) -> grid.sync -> loss ->
// grid.sync -> block-0 final reduce. 256 blocks x 512 threads = 1 block/CU.
// launch_bounds(512,1): VGPR budget 256/wave -> phase A's ~215 regs fit, no
// spills (R1's launch_bounds(512,2) capped at 128 -> scratch in inner loop).
// ---------------------------------------------------------------------------
__global__ __launch_bounds__(512, 1) void k_coop(const float* __restrict__ pred,
                                                 const int* __restrict__ target,
                                                 const float* __restrict__ draw,
                                                 float* __restrict__ cosmat,
                                                 float* __restrict__ psum,
                                                 int* __restrict__ pnz,
                                                 float* __restrict__ out) {
    const int b = blockIdx.x;
    const int tid = threadIdx.x;

    __shared__ float  ckA[NS], ckB[NS];
    __shared__ float4 v4sA[NS / 4], v4sB[NS / 4];
    __shared__ int    pkA[NS], pkB[NS];
    __shared__ float  spart[NS * 17];          // 34 KB
    __shared__ float  wf[8];
    __shared__ int    wi[8];
    __shared__ unsigned int pcA, pcB;

    // ================= phase A: gram, each element computed once ==========
    {
        const int ga = b >> 2;          // anchor group 0..63
        const int q  = b & 3;           // column quarter 0..3
        const int a0 = ga * 8;
        const int j0 = q * 128;

        const int w    = tid >> 6, lane = tid & 63;
        const int g    = lane >> 5;     // 0..1: row-within-step
        const int s    = lane & 31;     // 0..31: dim chunk

        const float4* p4 = (const float4*)pred;

        // anchor fragments: 8 anchors x 4 float4 = 128 VGPRs
        float4 fr[8][4];
#pragma unroll
        for (int a = 0; a < 8; a++) {
            const float4* pa = p4 + (size_t)(a0 + a) * (DE / 4);
#pragma unroll
            for (int p = 0; p < 4; p++) fr[a][p] = pa[p * 32 + s];
        }

        // anchor inverse norms (xor-reduce leaves value in all lanes)
        float rnA[8];
#pragma unroll
        for (int a = 0; a < 8; a++) {
            float aS = 0.0f;
#pragma unroll
            for (int p = 0; p < 4; p++) {
                float4 x = fr[a][p];
                aS = fmaf(x.x, x.x, aS); aS = fmaf(x.y, x.y, aS);
                aS = fmaf(x.z, x.z, aS); aS = fmaf(x.w, x.w, aS);
            }
#pragma unroll
            for (int m = 1; m <= 16; m <<= 1) aS += __shfl_xor(aS, m);
            rnA[a] = 1.0f / fmaxf(sqrtf(aS), 1e-8f);
        }

        // stream 16 rows per wave: j = j0 + w*16 + t*2 + g, 2-deep pipeline
        const float4* rj0 = p4 + (size_t)(j0 + w * 16 + g) * (DE / 4);
        const int rstep = 2 * (DE / 4);
        float4 x0[4], x1[4];
#pragma unroll
        for (int p = 0; p < 4; p++) x0[p] = rj0[p * 32 + s];
#pragma unroll
        for (int p = 0; p < 4; p++) x1[p] = rj0[rstep + p * 32 + s];

#pragma unroll
        for (int t = 0; t < 8; t++) {
            float4 xn[4];
            if (t < 6) {
                const float4* rjn = rj0 + (size_t)(t + 2) * rstep;
#pragma unroll
                for (int p = 0; p < 4; p++) xn[p] = rjn[p * 32 + s];
            }
            float acc[9];
#pragma unroll
            for (int a = 0; a < 9; a++) acc[a] = 0.0f;
#pragma unroll
            for (int p = 0; p < 4; p++) {
                float4 x = x0[p];
                acc[8] = fmaf(x.x, x.x, acc[8]); acc[8] = fmaf(x.y, x.y, acc[8]);
                acc[8] = fmaf(x.z, x.z, acc[8]); acc[8] = fmaf(x.w, x.w, acc[8]);
#pragma unroll
                for (int a = 0; a < 8; a++) {
                    float4 f = fr[a][p];
                    acc[a] = fmaf(x.x, f.x, acc[a]); acc[a] = fmaf(x.y, f.y, acc[a]);
                    acc[a] = fmaf(x.z, f.z, acc[a]); acc[a] = fmaf(x.w, f.w, acc[a]);
                }
            }
#pragma unroll
            for (int m = 1; m <= 16; m <<= 1) {
#pragma unroll
                for (int a = 0; a < 9; a++) acc[a] += __shfl_xor(acc[a], m);
            }
            if (s == 0) {
                const int jj = j0 + w * 16 + t * 2 + g;
                const float rnj = 1.0f / fmaxf(sqrtf(acc[8]), 1e-8f);
#pragma unroll
                for (int a = 0; a < 8; a++)
                    cosmat[(size_t)(a0 + a) * NS + jj] = acc[a] * rnA[a] * rnj;
            }
#pragma unroll
            for (int p = 0; p < 4; p++) { x0[p] = x1[p]; x1[p] = xn[p]; }
        }
    }

    cg::this_grid().sync();

    // ================= phase B: loss (anchors iA=b, iB=b+256) =============
    {
        const int iA = b, iB = b + 256;
        if (tid == 0) { pcA = 0u; pcB = 0u; }

        const int j = tid;
        const float cA = cosmat[(size_t)iA * NS + j];
        const float cB = cosmat[(size_t)iB * NS + j];

        float cp[NCL];
        cp[0] = 0.0f;
#pragma unroll
        for (int c = 0; c < NCL - 1; c++) cp[c + 1] = cp[c] + log1pf(expf(draw[c]));
        const int tiA = target[iA], tiB = target[iB];
        const float cpA = cp[tiA], cpB = cp[tiB];
        const int tj = target[j];
        const float cpj = cp[tj];
        __syncthreads();               // pcA/pcB init visible before atomics

        int nc;
        {   // anchor A
            bool n0 = (tj != tiA);
            ckA[j] = cA;
            ((float*)v4sA)[j] = n0 ? (cA + fabsf(cpA - cpj)) : -1e30f;
            if (!n0 && j != iA) pkA[atomicAdd(&pcA, 1u)] = j;
            nc = (n0 ? 1 : 0);
        }
        {   // anchor B (negcounts packed: A low 16, B high 16)
            bool n0 = (tj != tiB);
            ckB[j] = cB;
            ((float*)v4sB)[j] = n0 ? (cB + fabsf(cpB - cpj)) : -1e30f;
            if (!n0 && j != iB) pkB[atomicAdd(&pcB, 1u)] = j;
            nc += (n0 ? 1 : 0) << 16;
        }
#pragma unroll
        for (int m = 1; m <= 32; m <<= 1) nc += __shfl_xor(nc, m);
        if ((tid & 63) == 0) wi[tid >> 6] = nc;
        __syncthreads();   // covers wi AND the setup writes (ck/v4s/pk/pc)
        int negpack = 0;
#pragma unroll
        for (int q = 0; q < 8; q++) negpack += wi[q];
        const int negA = negpack & 0xffff;
        const int negB = negpack >> 16;
        const unsigned int nposA = pcA, nposB = pcB;

        const int kl = tid & 31, jc = tid >> 5;
        const float denA = (float)(negA > 1 ? negA : 1);
        const float denB = (float)(negB > 1 ? negB : 1);
        float contrib = 0.0f;
        int nzc = 0;

        {   // anchor A
            float4 vj[8];
#pragma unroll
            for (int t = 0; t < 8; t++) vj[t] = v4sA[jc * 8 + t];
            for (unsigned int p = kl; p < nposA; p += 32) {
                const float ckp = ckA[pkA[p]];
                float s0 = 0.0f, s1 = 0.0f;
#pragma unroll
                for (int t = 0; t < 8; t++) {
                    float4 wv = vj[t];
                    s0 += fmaxf(wv.x - ckp, 0.0f) + fmaxf(wv.y - ckp, 0.0f);
                    s1 += fmaxf(wv.z - ckp, 0.0f) + fmaxf(wv.w - ckp, 0.0f);
                }
                spart[p * 17 + jc] = s0 + s1;
            }
            __syncthreads();
            for (unsigned int p = tid; p < nposA; p += 512) {
                float s0 = 0.0f;
#pragma unroll
                for (int q = 0; q < 16; q++) s0 += spart[p * 17 + q];
                contrib += s0 / denA;
                if (s0 != 0.0f) nzc++;
            }
            __syncthreads();
        }
        {   // anchor B
            float4 vj[8];
#pragma unroll
            for (int t = 0; t < 8; t++) vj[t] = v4sB[jc * 8 + t];
            for (unsigned int p = kl; p < nposB; p += 32) {
                const float ckp = ckB[pkB[p]];
                float s0 = 0.0f, s1 = 0.0f;
#pragma unroll
                for (int t = 0; t < 8; t++) {
                    float4 wv = vj[t];
                    s0 += fmaxf(wv.x - ckp, 0.0f) + fmaxf(wv.y - ckp, 0.0f);
                    s1 += fmaxf(wv.z - ckp, 0.0f) + fmaxf(wv.w - ckp, 0.0f);
                }
                spart[p * 17 + jc] = s0 + s1;
            }
            __syncthreads();
            for (unsigned int p = tid; p < nposB; p += 512) {
                float s0 = 0.0f;
#pragma unroll
                for (int q = 0; q < 16; q++) s0 += spart[p * 17 + q];
                contrib += s0 / denB;
                if (s0 != 0.0f) nzc++;
            }
        }

        // ---- shuffle block reduction -> psum/pnz ----
#pragma unroll
        for (int m = 1; m <= 32; m <<= 1) {
            contrib += __shfl_xor(contrib, m);
            nzc     += __shfl_xor(nzc, m);
        }
        __syncthreads();   // protect wf/wi reuse
        if ((tid & 63) == 0) { wf[tid >> 6] = contrib; wi[tid >> 6] = nzc; }
        __syncthreads();
        if (tid == 0) {
            float sfin = 0.0f; int nfin = 0;
#pragma unroll
            for (int q = 0; q < 8; q++) { sfin += wf[q]; nfin += wi[q]; }
            psum[b] = sfin;
            pnz[b]  = nfin;
        }
    }

    cg::this_grid().sync();

    // ================= phase C: block-0 final reduce ======================
    if (b == 0) {
        if (tid < NBLK) { ckA[tid] = psum[tid]; pkA[tid] = pnz[tid]; }
        __syncthreads();
        for (int st = NBLK / 2; st > 0; st >>= 1) {
            if (tid < st) { ckA[tid] += ckA[tid + st]; pkA[tid] += pkA[tid + st]; }
            __syncthreads();
        }
        if (tid == 0) {
            int n = pkA[0];
            out[0] = ckA[0] / (float)(n > 1 ? n : 1);
        }
    }
}

extern "C" void kernel_launch(void* const* d_in, const int* in_sizes, int n_in,
                              void* d_out, int out_size, void* d_ws, size_t ws_size,
                              hipStream_t stream) {
    const float* pred   = (const float*)d_in[0];
    const float* draw   = (const float*)d_in[1];
    const int*   target = (const int*)d_in[2];
    float* out = (float*)d_out;

    float* cosmat = (float*)d_ws;                 // 512*512 floats = 1 MB
    float* psum   = cosmat + (size_t)NS * NS;     // 256 floats
    int*   pnz    = (int*)(psum + NBLK);          // 256 ints

    void* args[] = {(void*)&pred, (void*)&target, (void*)&draw,
                    (void*)&cosmat, (void*)&psum, (void*)&pnz, (void*)&out};
    hipLaunchCooperativeKernel((void*)k_coop, dim3(NBLK), dim3(512),
                               args, 0, stream);
}

// Round 3
// 82.411 us; speedup vs baseline: 1.7587x; 1.7587x over previous
//
#include <hip/hip_runtime.h>
#include <math.h>

#define NS 512
#define DE 512
#define NCL 5
#define NBLK 256

// ws layout: psum[256] | pnz[256]  (no ctrl, no memset — fully rewritten each launch)

// ---------------------------------------------------------------------------
// Fused kernel (R0 structure, phase 1 re-partitioned to kill VGPR spills).
// Block b: anchors iA=b, iB=b+256.
// Phase 1: 32-lane x 4-float4 per row (live set ~100 regs, fits 128 cap),
//          2-deep software pipeline (x0/x1/xn rotate), 32 steps x 2 rows/wave.
// Phase 2: block-local loss, shuffle reductions (unchanged, R13/R17-proven).
// ---------------------------------------------------------------------------
__global__ __launch_bounds__(512, 2) void k_all(const float* __restrict__ pred,
                                                const int* __restrict__ target,
                                                const float* __restrict__ draw,
                                                float* __restrict__ psum,
                                                int* __restrict__ pnz) {
    const int b = blockIdx.x;
    const int tid = threadIdx.x;
    const int iA = b, iB = b + 256;

    __shared__ float  rn_s[NS];
    __shared__ float  ckA[NS], ckB[NS];        // raw dots, then cos in place
    __shared__ float4 v4sA[NS / 4], v4sB[NS / 4];
    __shared__ int    pkA[NS], pkB[NS];
    __shared__ float  spart[NS * 17];          // 34 KB
    __shared__ float  wf[8];
    __shared__ int    wi[8];
    __shared__ unsigned int pcA, pcB;

    if (tid == 0) { pcA = 0u; pcB = 0u; }

    // ================= phase 1: spill-free pipelined triple dots ==========
    const int w = tid >> 6, lane = tid & 63;
    const int g = lane >> 5;     // 0..1: row-within-step
    const int s = lane & 31;     // 0..31: dim chunk (4 float4 each)

    const float4* pA = (const float4*)&pred[(size_t)iA * DE];
    const float4* pB = (const float4*)&pred[(size_t)iB * DE];
    float4 fA[4], fB[4];
#pragma unroll
    for (int p = 0; p < 4; p++) { fA[p] = pA[p * 32 + s]; fB[p] = pB[p * 32 + s]; }

    const float4* p4 = (const float4*)pred;
    const float4* rj0 = p4 + (size_t)(w * 64 + g) * (DE / 4);   // row for t=0
    const int rstep = 2 * (DE / 4);                              // +2 rows
    float4 x0[4], x1[4];
#pragma unroll
    for (int p = 0; p < 4; p++) x0[p] = rj0[p * 32 + s];
#pragma unroll
    for (int p = 0; p < 4; p++) x1[p] = rj0[rstep + p * 32 + s];

#pragma unroll
    for (int t = 0; t < 32; t++) {
        float4 xn[4];
        if (t < 30) {
            const float4* rjn = rj0 + (size_t)(t + 2) * rstep;
#pragma unroll
            for (int p = 0; p < 4; p++) xn[p] = rjn[p * 32 + s];  // 2 steps ahead
        }
        const int j = w * 64 + t * 2 + g;
        float aA = 0.0f, aB = 0.0f, aS = 0.0f;
#pragma unroll
        for (int p = 0; p < 4; p++) {
            float4 x = x0[p];
            aA = fmaf(x.x, fA[p].x, aA); aA = fmaf(x.y, fA[p].y, aA);
            aA = fmaf(x.z, fA[p].z, aA); aA = fmaf(x.w, fA[p].w, aA);
            aB = fmaf(x.x, fB[p].x, aB); aB = fmaf(x.y, fB[p].y, aB);
            aB = fmaf(x.z, fB[p].z, aB); aB = fmaf(x.w, fB[p].w, aB);
            aS = fmaf(x.x, x.x, aS);     aS = fmaf(x.y, x.y, aS);
            aS = fmaf(x.z, x.z, aS);     aS = fmaf(x.w, x.w, aS);
        }
#pragma unroll
        for (int m = 1; m <= 16; m <<= 1) {
            aA += __shfl_xor(aA, m);
            aB += __shfl_xor(aB, m);
            aS += __shfl_xor(aS, m);
        }
        if (s == 0) {
            ckA[j] = aA;
            ckB[j] = aB;
            rn_s[j] = 1.0f / fmaxf(sqrtf(aS), 1e-8f);
        }
#pragma unroll
        for (int p = 0; p < 4; p++) { x0[p] = x1[p]; x1[p] = xn[p]; }
    }

    // ordinal class positions
    float cp[NCL];
    cp[0] = 0.0f;
#pragma unroll
    for (int c = 0; c < NCL - 1; c++) cp[c + 1] = cp[c] + log1pf(expf(draw[c]));
    const int tiA = target[iA], tiB = target[iB];
    const float cpA = cp[tiA], cpB = cp[tiB];
    const int j = tid;
    const int tj = target[j];
    const float cpj = cp[tj];
    __syncthreads();

    // ================= phase 2: loss setup =================
    const float rniA = rn_s[iA], rniB = rn_s[iB], rnj = rn_s[j];
    int nc;
    {   // anchor A
        float c0 = ckA[j] * rniA * rnj;
        bool n0 = (tj != tiA);
        ckA[j] = c0;
        ((float*)v4sA)[j] = n0 ? (c0 + fabsf(cpA - cpj)) : -1e30f;
        if (!n0 && j != iA) pkA[atomicAdd(&pcA, 1u)] = j;
        nc = (n0 ? 1 : 0);
    }
    {   // anchor B (negcounts packed: A low 16, B high 16)
        float c0 = ckB[j] * rniB * rnj;
        bool n0 = (tj != tiB);
        ckB[j] = c0;
        ((float*)v4sB)[j] = n0 ? (c0 + fabsf(cpB - cpj)) : -1e30f;
        if (!n0 && j != iB) pkB[atomicAdd(&pcB, 1u)] = j;
        nc += (n0 ? 1 : 0) << 16;
    }
    // shuffle reduce negcounts (64-lane wave), leaders -> wi[8]
#pragma unroll
    for (int m = 1; m <= 32; m <<= 1) nc += __shfl_xor(nc, m);
    if ((tid & 63) == 0) wi[tid >> 6] = nc;
    __syncthreads();   // covers wi AND the setup writes (ck/v4s/pk/pc)
    int negpack = 0;
#pragma unroll
    for (int q = 0; q < 8; q++) negpack += wi[q];
    const int negA = negpack & 0xffff;
    const int negB = negpack >> 16;
    const unsigned int nposA = pcA, nposB = pcB;

    // pass1 split: 32 k-lanes x 16 j-chunks (32 j's each, cached in VGPRs)
    const int kl = tid & 31, jc = tid >> 5;
    const float denA = (float)(negA > 1 ? negA : 1);
    const float denB = (float)(negB > 1 ? negB : 1);
    float contrib = 0.0f;
    int nzc = 0;

    {   // anchor A
        float4 vj[8];
#pragma unroll
        for (int t = 0; t < 8; t++) vj[t] = v4sA[jc * 8 + t];
        for (unsigned int p = kl; p < nposA; p += 32) {
            const float ckp = ckA[pkA[p]];
            float s0 = 0.0f, s1 = 0.0f;
#pragma unroll
            for (int t = 0; t < 8; t++) {
                float4 wv = vj[t];
                s0 += fmaxf(wv.x - ckp, 0.0f) + fmaxf(wv.y - ckp, 0.0f);
                s1 += fmaxf(wv.z - ckp, 0.0f) + fmaxf(wv.w - ckp, 0.0f);
            }
            spart[p * 17 + jc] = s0 + s1;
        }
        __syncthreads();
        for (unsigned int p = tid; p < nposA; p += 512) {
            float s0 = 0.0f;
#pragma unroll
            for (int q = 0; q < 16; q++) s0 += spart[p * 17 + q];
            contrib += s0 / denA;
            if (s0 != 0.0f) nzc++;
        }
        __syncthreads();
    }
    {   // anchor B
        float4 vj[8];
#pragma unroll
        for (int t = 0; t < 8; t++) vj[t] = v4sB[jc * 8 + t];
        for (unsigned int p = kl; p < nposB; p += 32) {
            const float ckp = ckB[pkB[p]];
            float s0 = 0.0f, s1 = 0.0f;
#pragma unroll
            for (int t = 0; t < 8; t++) {
                float4 wv = vj[t];
                s0 += fmaxf(wv.x - ckp, 0.0f) + fmaxf(wv.y - ckp, 0.0f);
                s1 += fmaxf(wv.z - ckp, 0.0f) + fmaxf(wv.w - ckp, 0.0f);
            }
            spart[p * 17 + jc] = s0 + s1;
        }
        __syncthreads();
        for (unsigned int p = tid; p < nposB; p += 512) {
            float s0 = 0.0f;
#pragma unroll
            for (int q = 0; q < 16; q++) s0 += spart[p * 17 + q];
            contrib += s0 / denB;
            if (s0 != 0.0f) nzc++;
        }
    }

    // ---- shuffle block reduction, partials to distinct cachelines ----
#pragma unroll
    for (int m = 1; m <= 32; m <<= 1) {
        contrib += __shfl_xor(contrib, m);
        nzc     += __shfl_xor(nzc, m);
    }
    __syncthreads();   // protect wf/wi reuse
    if ((tid & 63) == 0) { wf[tid >> 6] = contrib; wi[tid >> 6] = nzc; }
    __syncthreads();
    if (tid == 0) {
        float sfin = 0.0f; int nfin = 0;
#pragma unroll
        for (int q = 0; q < 8; q++) { sfin += wf[q]; nfin += wi[q]; }
        psum[b] = sfin;
        pnz[b]  = nfin;
    }
}

// ---------------------------------------------------------------------------
// Final: reduce 256 partials, out = sum / max(nz, 1)
// ---------------------------------------------------------------------------
__global__ __launch_bounds__(256) void k_final(const float* __restrict__ psum,
                                               const int* __restrict__ pnz,
                                               float* __restrict__ out) {
    const int tid = threadIdx.x;
    __shared__ float rf[256];
    __shared__ int   ri[256];
    rf[tid] = psum[tid];
    ri[tid] = pnz[tid];
    __syncthreads();
    for (int s = 128; s > 0; s >>= 1) {
        if (tid < s) { rf[tid] += rf[tid + s]; ri[tid] += ri[tid + s]; }
        __syncthreads();
    }
    if (tid == 0) {
        int n = ri[0];
        out[0] = rf[0] / (float)(n > 1 ? n : 1);
    }
}

extern "C" void kernel_launch(void* const* d_in, const int* in_sizes, int n_in,
                              void* d_out, int out_size, void* d_ws, size_t ws_size,
                              hipStream_t stream) {
    const float* pred   = (const float*)d_in[0];
    const float* draw   = (const float*)d_in[1];
    const int*   target = (const int*)d_in[2];
    float* out = (float*)d_out;

    float* psum = (float*)d_ws;                  // 256 floats
    int*   pnz  = (int*)(psum + NBLK);           // 256 ints

    hipLaunchKernelGGL(k_all, dim3(NBLK), dim3(512), 0, stream,
                       pred, target, draw, psum, pnz);
    hipLaunchKernelGGL(k_final, dim3(1), dim3(256), 0, stream, psum, pnz, out);
}

// Round 4
// 76.516 us; speedup vs baseline: 1.8942x; 1.0770x over previous
//
#include <hip/hip_runtime.h>
#include <math.h>

#define NS 512
#define DE 512
#define NCL 5
#define NBLK 256

// ws layout: psum[256] | pnz[256]  (no ctrl, no memset — fully rewritten each launch)

// ---------------------------------------------------------------------------
// Fused kernel (R17 structure — best measured: 76.2 us).
// Block b: anchors iA=b, iB=b+256.
// Phase 1: coalesced triple-dot, 2-DEEP software pipeline (x0/x1/xn rotate).
// Phase 2: block-local loss, shuffle reductions (no LDS trees).
// Ending: plain partial stores to distinct lines (R13-proven) + k_final.
// NOTE (R4 post-mortem): dispatch accounting calibrated on the R2 cooperative
// run shows ~72 us of dur_us is harness-fixed (256 MiB poison fill at 84% HBM
// peak + ~30 reset dispatches); k_all+k_final are ~4 us combined. Structural
// rewrites (3-kernel split, cooperative fusion, 32x4 repartition) all
// regressed. This is the proven optimum — do not restructure without
// evidence the fixed overhead model is wrong.
// ---------------------------------------------------------------------------
__global__ __launch_bounds__(512, 2) void k_all(const float* __restrict__ pred,
                                                const int* __restrict__ target,
                                                const float* __restrict__ draw,
                                                float* __restrict__ psum,
                                                int* __restrict__ pnz) {
    const int b = blockIdx.x;
    const int tid = threadIdx.x;
    const int iA = b, iB = b + 256;

    __shared__ float  rn_s[NS];
    __shared__ float  ckA[NS], ckB[NS];        // raw dots, then cos in place
    __shared__ float4 v4sA[NS / 4], v4sB[NS / 4];
    __shared__ int    pkA[NS], pkB[NS];
    __shared__ float  spart[NS * 17];          // 34 KB
    __shared__ float  wf[8];
    __shared__ int    wi[8];
    __shared__ unsigned int pcA, pcB;

    if (tid == 0) { pcA = 0u; pcB = 0u; }

    // ================= phase 1: 2-deep pipelined triple dots ============
    const int w = tid >> 6, lane = tid & 63;
    const int g = lane >> 4, s = lane & 15;

    const float4* pA = (const float4*)&pred[(size_t)iA * DE];
    const float4* pB = (const float4*)&pred[(size_t)iB * DE];
    float4 fA[8], fB[8];
#pragma unroll
    for (int p = 0; p < 8; p++) { fA[p] = pA[p * 16 + s]; fB[p] = pB[p * 16 + s]; }

    const float4* p4 = (const float4*)pred;
    const float4* rj0 = p4 + (size_t)(w * 64 + g) * (DE / 4);   // row for t=0
    const int rstep = 4 * (DE / 4);                              // +4 rows
    float4 x0[8], x1[8];
#pragma unroll
    for (int p = 0; p < 8; p++) x0[p] = rj0[p * 16 + s];
#pragma unroll
    for (int p = 0; p < 8; p++) x1[p] = rj0[rstep + p * 16 + s];

#pragma unroll
    for (int t = 0; t < 16; t++) {
        float4 xn[8];
        if (t < 14) {
            const float4* rjn = rj0 + (size_t)(t + 2) * rstep;
#pragma unroll
            for (int p = 0; p < 8; p++) xn[p] = rjn[p * 16 + s];  // in flight 2 steps
        }
        const int j = w * 64 + t * 4 + g;
        float aA = 0.0f, aB = 0.0f, aS = 0.0f;
#pragma unroll
        for (int p = 0; p < 8; p++) {
            float4 x = x0[p];
            aA = fmaf(x.x, fA[p].x, aA); aA = fmaf(x.y, fA[p].y, aA);
            aA = fmaf(x.z, fA[p].z, aA); aA = fmaf(x.w, fA[p].w, aA);
            aB = fmaf(x.x, fB[p].x, aB); aB = fmaf(x.y, fB[p].y, aB);
            aB = fmaf(x.z, fB[p].z, aB); aB = fmaf(x.w, fB[p].w, aB);
            aS = fmaf(x.x, x.x, aS);     aS = fmaf(x.y, x.y, aS);
            aS = fmaf(x.z, x.z, aS);     aS = fmaf(x.w, x.w, aS);
        }
#pragma unroll
        for (int m = 1; m <= 8; m <<= 1) {
            aA += __shfl_xor(aA, m);
            aB += __shfl_xor(aB, m);
            aS += __shfl_xor(aS, m);
        }
        if (s == 0) {
            ckA[j] = aA;
            ckB[j] = aB;
            rn_s[j] = 1.0f / fmaxf(sqrtf(aS), 1e-8f);
        }
#pragma unroll
        for (int p = 0; p < 8; p++) { x0[p] = x1[p]; x1[p] = xn[p]; }
    }

    // ordinal class positions
    float cp[NCL];
    cp[0] = 0.0f;
#pragma unroll
    for (int c = 0; c < NCL - 1; c++) cp[c + 1] = cp[c] + log1pf(expf(draw[c]));
    const int tiA = target[iA], tiB = target[iB];
    const float cpA = cp[tiA], cpB = cp[tiB];
    const int j = tid;
    const int tj = target[j];
    const float cpj = cp[tj];
    __syncthreads();

    // ================= phase 2: loss setup =================
    const float rniA = rn_s[iA], rniB = rn_s[iB], rnj = rn_s[j];
    int nc;
    {   // anchor A
        float c0 = ckA[j] * rniA * rnj;
        bool n0 = (tj != tiA);
        ckA[j] = c0;
        ((float*)v4sA)[j] = n0 ? (c0 + fabsf(cpA - cpj)) : -1e30f;
        if (!n0 && j != iA) pkA[atomicAdd(&pcA, 1u)] = j;
        nc = (n0 ? 1 : 0);
    }
    {   // anchor B (negcounts packed: A low 16, B high 16)
        float c0 = ckB[j] * rniB * rnj;
        bool n0 = (tj != tiB);
        ckB[j] = c0;
        ((float*)v4sB)[j] = n0 ? (c0 + fabsf(cpB - cpj)) : -1e30f;
        if (!n0 && j != iB) pkB[atomicAdd(&pcB, 1u)] = j;
        nc += (n0 ? 1 : 0) << 16;
    }
    // shuffle reduce negcounts (64-lane wave), leaders -> wi[8]
#pragma unroll
    for (int m = 1; m <= 32; m <<= 1) nc += __shfl_xor(nc, m);
    if ((tid & 63) == 0) wi[tid >> 6] = nc;
    __syncthreads();   // covers wi AND the setup writes (ck/v4s/pk/pc)
    int negpack = 0;
#pragma unroll
    for (int q = 0; q < 8; q++) negpack += wi[q];
    const int negA = negpack & 0xffff;
    const int negB = negpack >> 16;
    const unsigned int nposA = pcA, nposB = pcB;

    // pass1 split: 32 k-lanes x 16 j-chunks (32 j's each, cached in VGPRs)
    const int kl = tid & 31, jc = tid >> 5;
    const float denA = (float)(negA > 1 ? negA : 1);
    const float denB = (float)(negB > 1 ? negB : 1);
    float contrib = 0.0f;
    int nzc = 0;

    {   // anchor A
        float4 vj[8];
#pragma unroll
        for (int t = 0; t < 8; t++) vj[t] = v4sA[jc * 8 + t];
        for (unsigned int p = kl; p < nposA; p += 32) {
            const float ckp = ckA[pkA[p]];
            float s0 = 0.0f, s1 = 0.0f;
#pragma unroll
            for (int t = 0; t < 8; t++) {
                float4 wv = vj[t];
                s0 += fmaxf(wv.x - ckp, 0.0f) + fmaxf(wv.y - ckp, 0.0f);
                s1 += fmaxf(wv.z - ckp, 0.0f) + fmaxf(wv.w - ckp, 0.0f);
            }
            spart[p * 17 + jc] = s0 + s1;
        }
        __syncthreads();
        for (unsigned int p = tid; p < nposA; p += 512) {
            float s0 = 0.0f;
#pragma unroll
            for (int q = 0; q < 16; q++) s0 += spart[p * 17 + q];
            contrib += s0 / denA;
            if (s0 != 0.0f) nzc++;
        }
        __syncthreads();
    }
    {   // anchor B
        float4 vj[8];
#pragma unroll
        for (int t = 0; t < 8; t++) vj[t] = v4sB[jc * 8 + t];
        for (unsigned int p = kl; p < nposB; p += 32) {
            const float ckp = ckB[pkB[p]];
            float s0 = 0.0f, s1 = 0.0f;
#pragma unroll
            for (int t = 0; t < 8; t++) {
                float4 wv = vj[t];
                s0 += fmaxf(wv.x - ckp, 0.0f) + fmaxf(wv.y - ckp, 0.0f);
                s1 += fmaxf(wv.z - ckp, 0.0f) + fmaxf(wv.w - ckp, 0.0f);
            }
            spart[p * 17 + jc] = s0 + s1;
        }
        __syncthreads();
        for (unsigned int p = tid; p < nposB; p += 512) {
            float s0 = 0.0f;
#pragma unroll
            for (int q = 0; q < 16; q++) s0 += spart[p * 17 + q];
            contrib += s0 / denB;
            if (s0 != 0.0f) nzc++;
        }
    }

    // ---- shuffle block reduction, partials to distinct cachelines ----
#pragma unroll
    for (int m = 1; m <= 32; m <<= 1) {
        contrib += __shfl_xor(contrib, m);
        nzc     += __shfl_xor(nzc, m);
    }
    __syncthreads();   // protect wf/wi reuse
    if ((tid & 63) == 0) { wf[tid >> 6] = contrib; wi[tid >> 6] = nzc; }
    __syncthreads();
    if (tid == 0) {
        float sfin = 0.0f; int nfin = 0;
#pragma unroll
        for (int q = 0; q < 8; q++) { sfin += wf[q]; nfin += wi[q]; }
        psum[b] = sfin;
        pnz[b]  = nfin;
    }
}

// ---------------------------------------------------------------------------
// Final: reduce 256 partials, out = sum / max(nz, 1)
// ---------------------------------------------------------------------------
__global__ __launch_bounds__(256) void k_final(const float* __restrict__ psum,
                                               const int* __restrict__ pnz,
                                               float* __restrict__ out) {
    const int tid = threadIdx.x;
    __shared__ float rf[256];
    __shared__ int   ri[256];
    rf[tid] = psum[tid];
    ri[tid] = pnz[tid];
    __syncthreads();
    for (int s = 128; s > 0; s >>= 1) {
        if (tid < s) { rf[tid] += rf[tid + s]; ri[tid] += ri[tid + s]; }
        __syncthreads();
    }
    if (tid == 0) {
        int n = ri[0];
        out[0] = rf[0] / (float)(n > 1 ? n : 1);
    }
}

extern "C" void kernel_launch(void* const* d_in, const int* in_sizes, int n_in,
                              void* d_out, int out_size, void* d_ws, size_t ws_size,
                              hipStream_t stream) {
    const float* pred   = (const float*)d_in[0];
    const float* draw   = (const float*)d_in[1];
    const int*   target = (const int*)d_in[2];
    float* out = (float*)d_out;

    float* psum = (float*)d_ws;                  // 256 floats
    int*   pnz  = (int*)(psum + NBLK);           // 256 ints

    hipLaunchKernelGGL(k_all, dim3(NBLK), dim3(512), 0, stream,
                       pred, target, draw, psum, pnz);
    hipLaunchKernelGGL(k_final, dim3(1), dim3(256), 0, stream, psum, pnz, out);
}